// Round 1
// baseline (1071.017 us; speedup 1.0000x reference)
//
#include <hip/hip_runtime.h>
#include <hip/hip_bf16.h>

namespace {

constexpr int L = 8192;
constexpr int D = 256;
constexpr int EXS = 33;   // LDS exchange stride (words) — breaks bank conflicts

// K1: levels 0..5 (dilation 1..32). Block: 8 tt-groups x 32 channels.
constexpr int K1_TC  = 32;   // channels per block
constexpr int K1_R   = 32;   // t per thread
constexpr int K1_OUT = 192;  // valid outputs per block (64-step halo)

// K2: levels 6..12 (dilation 64..4096 = t1-dilation 1..64). Block: 4 tt x 64 ch.
constexpr int K2_TC = 64;
constexpr int K2_R  = 32;    // t1 per thread; 4*32 = 128 = full t1 range

__device__ __forceinline__ float ld_a6(const float* p) { return *p; }
__device__ __forceinline__ float ld_a6(const __hip_bfloat16* p) { return __bfloat162float(*p); }
__device__ __forceinline__ void st_a6(float* p, float v) { *p = v; }
__device__ __forceinline__ void st_a6(__hip_bfloat16* p, float v) { *p = __float2bfloat16(v); }

// ---------------- Kernel 1: levels 0..5 ----------------
// Each thread owns 32 consecutive t of one channel, in registers.
// Stage range per block: [t0-64, t0+192). First 64 staged t are halo:
// true zeros for block 0 (t<0), garbage-but-discarded otherwise
// (contamination after levels 0..5 reaches only staged pos < 63 < 64).
template <typename TA>
__global__ __launch_bounds__(256, 4)
void mrl_k1(const float* __restrict__ x, const float* __restrict__ h0,
            const float* __restrict__ h1, const float* __restrict__ w,
            float* __restrict__ y1, TA* __restrict__ a6) {
    __shared__ float ex[256 * EXS];
    const int tid = threadIdx.x;
    const int tc  = tid & (K1_TC - 1);
    const int tt  = tid / K1_TC;              // 0..7
    const int c   = blockIdx.y * K1_TC + tc;
    const int b   = blockIdx.z;
    const int t0  = blockIdx.x * K1_OUT;
    const int ts  = t0 - 64 + tt * K1_R;      // first staged t of this thread

    const float h0c0 = h0[2*c], h0c1 = h0[2*c+1];
    const float h1c0 = h1[2*c], h1c1 = h1[2*c+1];
    const float w0   = w[c];

    const float* xp = x + (size_t)b * L * D + c;
    float a[K1_R], y[K1_R];
#pragma unroll
    for (int i = 0; i < K1_R; ++i) {
        const int t = ts + i;
        float v = 0.f;
        if (t >= 0 && t < L) v = xp[(size_t)t * D];
        a[i] = v;
        y[i] = w0 * v;
    }

#pragma unroll
    for (int j = 0; j < 6; ++j) {
        const int d = 1 << j;                 // compile-time after unroll
        const float wj = w[(j + 1) * D + c];
        // publish top d values (old a) for the right neighbor
#pragma unroll
        for (int k = 0; k < d; ++k) ex[tid * EXS + k] = a[K1_R - d + k];
        __syncthreads();
        const int nsrc = (tt > 0) ? (tid - K1_TC) : tid;  // clamped, value masked below
        // descending i: lookback i-d always reads not-yet-updated regs
#pragma unroll
        for (int i = K1_R - 1; i >= 0; --i) {
            float look;
            if (i >= d) {
                look = a[i - d];
            } else {
                const float hv = ex[nsrc * EXS + i];
                look = (tt > 0) ? hv : 0.f;
            }
            const float bv = look * h1c0 + a[i] * h1c1;
            y[i] = fmaf(wj, bv, y[i]);
            a[i] = look * h0c0 + a[i] * h0c1;
        }
        __syncthreads();  // protect ex before next level's publish
    }

    if (tt >= 2) {  // only valid outputs [t0, t0+192)
        float* yp = y1 + (size_t)b * L * D + c;
        TA*    ap = a6 + (size_t)b * L * D + c;
#pragma unroll
        for (int i = 0; i < K1_R; ++i) {
            const int t = ts + i;
            if (t < L) {
                yp[(size_t)t * D] = y[i];
                st_a6(&ap[(size_t)t * D], a[i]);
            }
        }
    }
}

// ---------------- Kernel 2: levels 6..12 + final terms ----------------
// For t = t1*64 + t2, levels 6..12 only couple along t1 (length 128).
// Block = (t2, 64-channel tile, b); thread owns 32 consecutive t1 of one channel.
template <typename TA>
__global__ __launch_bounds__(256, 4)
void mrl_k2(const TA* __restrict__ a6, const float* __restrict__ h0,
            const float* __restrict__ h1, const float* __restrict__ w,
            float* __restrict__ y) {
    __shared__ float ex[256 * EXS];
    const int tid = threadIdx.x;
    const int tc  = tid & (K2_TC - 1);
    const int tt  = tid / K2_TC;              // 0..3
    const int t2  = blockIdx.x;               // 0..63
    const int c   = blockIdx.y * K2_TC + tc;
    const int b   = blockIdx.z;

    const float h0c0 = h0[2*c], h0c1 = h0[2*c+1];
    const float h1c0 = h1[2*c], h1c1 = h1[2*c+1];

    const size_t base = ((size_t)b * L + t2) * D + c;   // t1 stride = 64*D
    float a[K2_R], yv[K2_R];
#pragma unroll
    for (int i = 0; i < K2_R; ++i) {
        const size_t off = base + (size_t)(tt * K2_R + i) * 64 * D;
        a[i]  = ld_a6(&a6[off]);
        yv[i] = y[off];            // y1 from kernel 1
    }

#pragma unroll
    for (int j = 0; j < 7; ++j) {
        const int d = 1 << j;                 // t1-units: 1..64
        const float wj = w[(j + 7) * D + c];
        const int np  = (d < K2_R) ? d : K2_R;
        const int off = (d < K2_R) ? (K2_R - d) : 0;
#pragma unroll
        for (int k = 0; k < np; ++k) ex[tid * EXS + k] = a[off + k];
        __syncthreads();
        if (d <= K2_R) {
            const int nsrc = (tt > 0) ? (tid - K2_TC) : tid;
#pragma unroll
            for (int i = K2_R - 1; i >= 0; --i) {
                float look;
                if (i >= d) {
                    look = a[i - d];
                } else {
                    const float hv = ex[nsrc * EXS + i];
                    look = (tt > 0) ? hv : 0.f;
                }
                const float bv = look * h1c0 + a[i] * h1c1;
                yv[i] = fmaf(wj, bv, yv[i]);
                a[i] = look * h0c0 + a[i] * h0c1;
            }
        } else {  // d == 64: halo = full slab of neighbor-2
            const int nsrc = (tt > 1) ? (tid - 2 * K2_TC) : tid;
#pragma unroll
            for (int i = K2_R - 1; i >= 0; --i) {
                const float hv = ex[nsrc * EXS + i];
                const float look = (tt > 1) ? hv : 0.f;
                const float bv = look * h1c0 + a[i] * h1c1;
                yv[i] = fmaf(wj, bv, yv[i]);
                a[i] = look * h0c0 + a[i] * h0c1;
            }
        }
        __syncthreads();
    }

    const float w14 = w[14 * D + c];
#pragma unroll
    for (int i = 0; i < K2_R; ++i) {
        yv[i] = fmaf(w14, a[i], yv[i]);
        y[base + (size_t)(tt * K2_R + i) * 64 * D] = yv[i];
    }
}

} // namespace

extern "C" void kernel_launch(void* const* d_in, const int* in_sizes, int n_in,
                              void* d_out, int out_size, void* d_ws, size_t ws_size,
                              hipStream_t stream) {
    const float* x  = (const float*)d_in[0];
    const float* h0 = (const float*)d_in[1];
    const float* h1 = (const float*)d_in[2];
    const float* w  = (const float*)d_in[3];
    float* y = (float*)d_out;

    const int B = in_sizes[0] / (L * D);   // = 8
    const size_t need_f32 = (size_t)B * L * D * sizeof(float);

    dim3 g1((L + K1_OUT - 1) / K1_OUT, D / K1_TC, B);  // (43, 8, 8)
    dim3 g2(64, D / K2_TC, B);                          // (64, 4, 8)

    if (ws_size >= need_f32) {
        float* a6 = (float*)d_ws;
        mrl_k1<float><<<g1, 256, 0, stream>>>(x, h0, h1, w, y, a6);
        mrl_k2<float><<<g2, 256, 0, stream>>>(a6, h0, h1, w, y);
    } else {
        // scratch too small for fp32 intermediate: store a6 as bf16 (32 MB).
        // Rounding error ~0.4% relative, far under the 1.185 absmax threshold.
        __hip_bfloat16* a6 = (__hip_bfloat16*)d_ws;
        mrl_k1<__hip_bfloat16><<<g1, 256, 0, stream>>>(x, h0, h1, w, y, a6);
        mrl_k2<__hip_bfloat16><<<g2, 256, 0, stream>>>(a6, h0, h1, w, y);
    }
}

// Round 2
// 460.272 us; speedup vs baseline: 2.3269x; 2.3269x over previous
//
#include <hip/hip_runtime.h>
#include <hip/hip_bf16.h>
#include <stdint.h>

namespace {

constexpr int L = 8192;
constexpr int D = 256;
constexpr int EXS = 33;   // LDS exchange stride (words) — odd => no bank conflicts

// K1: levels 0..5 (dilation 1..32). Block: 8 tt-groups x 32 channels.
constexpr int K1_TC  = 32;   // channels per block
constexpr int K1_R   = 32;   // t per thread
constexpr int K1_OUT = 192;  // valid outputs per block (64-step halo)

// K2: levels 6..12 (t1-dilation 1..64). Block: 4 tt x 64 channels.
constexpr int K2_TC = 64;
constexpr int K2_R  = 32;    // t1 per thread; 4*32 = 128 = full t1 range

// pack {bf16(y1) in low 16, bf16(a6) in high 16}
__device__ __forceinline__ uint32_t pk2(float ylo, float ahi) {
    union { __hip_bfloat16 h; uint16_t u; } a, b;
    a.h = __float2bfloat16(ylo);
    b.h = __float2bfloat16(ahi);
    return ((uint32_t)b.u << 16) | (uint32_t)a.u;
}
__device__ __forceinline__ float up_lo(uint32_t u) { return __uint_as_float(u << 16); }
__device__ __forceinline__ float up_hi(uint32_t u) { return __uint_as_float(u & 0xffff0000u); }

// ---------------- Kernel 1: levels 0..5 ----------------
// Each thread owns 32 consecutive t of one channel, fully in registers.
// Staged range per block: [t0-64, t0+192). First 64 staged t are halo
// (true x values for t>=0, zeros for t<0); outputs written only for
// staged pos >= 64, whose 63-deep receptive field stays inside the stage.
__global__ __launch_bounds__(256, 2)
void mrl_k1(const float* __restrict__ x, const float* __restrict__ h0,
            const float* __restrict__ h1, const float* __restrict__ w,
            uint32_t* __restrict__ out_pk) {
    __shared__ float ex[256 * EXS];
    const int tid = threadIdx.x;
    const int tc  = tid & (K1_TC - 1);
    const int tt  = tid / K1_TC;              // 0..7
    const int c   = blockIdx.y * K1_TC + tc;
    const int b   = blockIdx.z;
    const int t0  = blockIdx.x * K1_OUT;
    const int ts  = t0 - 64 + tt * K1_R;      // first staged t of this thread

    const float h0c0 = h0[2*c], h0c1 = h0[2*c+1];
    const float h1c0 = h1[2*c], h1c1 = h1[2*c+1];
    const float w0   = w[c];

    const float* xp = x + (size_t)b * L * D + c;
    float a[K1_R], y[K1_R];
#pragma unroll
    for (int i = 0; i < K1_R; ++i) {
        const int t = ts + i;
        float v = 0.f;
        if (t >= 0 && t < L) v = xp[(size_t)t * D];
        a[i] = v;
        y[i] = w0 * v;
    }

#pragma unroll
    for (int j = 0; j < 6; ++j) {
        const int d = 1 << j;                 // compile-time after unroll
        const float wj = w[(j + 1) * D + c];
        // publish top d values (old a) for the right neighbor
#pragma unroll
        for (int k = 0; k < d; ++k) ex[tid * EXS + k] = a[K1_R - d + k];
        __syncthreads();
        const int nsrc = (tt > 0) ? (tid - K1_TC) : tid;  // clamped; value masked below
        // descending i: lookback i-d always reads not-yet-updated regs
#pragma unroll
        for (int i = K1_R - 1; i >= 0; --i) {
            float look;
            if (i >= d) {
                look = a[i - d];
            } else {
                const float hv = ex[nsrc * EXS + i];
                look = (tt > 0) ? hv : 0.f;
            }
            const float bv = look * h1c0 + a[i] * h1c1;
            y[i] = fmaf(wj, bv, y[i]);
            a[i] = look * h0c0 + a[i] * h0c1;
        }
        __syncthreads();  // protect ex before next level's publish
    }

    if (tt >= 2) {  // only valid outputs [t0, t0+192)
        uint32_t* op = out_pk + (size_t)b * L * D + c;
#pragma unroll
        for (int i = 0; i < K1_R; ++i) {
            const int t = ts + i;
            if (t < L) op[(size_t)t * D] = pk2(y[i], a[i]);
        }
    }
}

// ---------------- Kernel 2: levels 6..12 + final terms ----------------
// For t = t1*64 + t2, levels 6..12 couple only along t1 (length 128).
// Block = (t2, 64-channel tile, b); thread owns 32 consecutive t1 of one
// channel. Reads the packed {y1,a6} words from d_out, overwrites in place
// with final f32 y (each word read & written by the same thread).
__global__ __launch_bounds__(256, 2)
void mrl_k2(const float* __restrict__ h0, const float* __restrict__ h1,
            const float* __restrict__ w, float* __restrict__ y) {
    __shared__ float ex[256 * EXS];
    const uint32_t* yin = (const uint32_t*)y;
    const int tid = threadIdx.x;
    const int tc  = tid & (K2_TC - 1);
    const int tt  = tid / K2_TC;              // 0..3
    const int t2  = blockIdx.x;               // 0..63
    const int c   = blockIdx.y * K2_TC + tc;
    const int b   = blockIdx.z;

    const float h0c0 = h0[2*c], h0c1 = h0[2*c+1];
    const float h1c0 = h1[2*c], h1c1 = h1[2*c+1];

    const size_t base = ((size_t)b * L + t2) * D + c;   // t1 stride = 64*D
    float a[K2_R], yv[K2_R];
#pragma unroll
    for (int i = 0; i < K2_R; ++i) {
        const uint32_t u = yin[base + (size_t)(tt * K2_R + i) * 64 * D];
        a[i]  = up_hi(u);
        yv[i] = up_lo(u);
    }

#pragma unroll
    for (int j = 0; j < 7; ++j) {
        const int d = 1 << j;                 // t1-units: 1..64
        const float wj = w[(j + 7) * D + c];
        const int np  = (d < K2_R) ? d : K2_R;
        const int off = (d < K2_R) ? (K2_R - d) : 0;
#pragma unroll
        for (int k = 0; k < np; ++k) ex[tid * EXS + k] = a[off + k];
        __syncthreads();
        if (d <= K2_R) {
            const int nsrc = (tt > 0) ? (tid - K2_TC) : tid;
#pragma unroll
            for (int i = K2_R - 1; i >= 0; --i) {
                float look;
                if (i >= d) {
                    look = a[i - d];
                } else {
                    const float hv = ex[nsrc * EXS + i];
                    look = (tt > 0) ? hv : 0.f;
                }
                const float bv = look * h1c0 + a[i] * h1c1;
                yv[i] = fmaf(wj, bv, yv[i]);
                a[i] = look * h0c0 + a[i] * h0c1;
            }
        } else {  // d == 64: halo = full slab of neighbor-2
            const int nsrc = (tt > 1) ? (tid - 2 * K2_TC) : tid;
#pragma unroll
            for (int i = K2_R - 1; i >= 0; --i) {
                const float hv = ex[nsrc * EXS + i];
                const float look = (tt > 1) ? hv : 0.f;
                const float bv = look * h1c0 + a[i] * h1c1;
                yv[i] = fmaf(wj, bv, yv[i]);
                a[i] = look * h0c0 + a[i] * h0c1;
            }
        }
        __syncthreads();
    }

    const float w14 = w[14 * D + c];
#pragma unroll
    for (int i = 0; i < K2_R; ++i) {
        yv[i] = fmaf(w14, a[i], yv[i]);
        y[base + (size_t)(tt * K2_R + i) * 64 * D] = yv[i];
    }
}

} // namespace

extern "C" void kernel_launch(void* const* d_in, const int* in_sizes, int n_in,
                              void* d_out, int out_size, void* d_ws, size_t ws_size,
                              hipStream_t stream) {
    const float* x  = (const float*)d_in[0];
    const float* h0 = (const float*)d_in[1];
    const float* h1 = (const float*)d_in[2];
    const float* w  = (const float*)d_in[3];
    float* y = (float*)d_out;
    (void)d_ws; (void)ws_size;

    const int B = in_sizes[0] / (L * D);   // = 8

    dim3 g1((L + K1_OUT - 1) / K1_OUT, D / K1_TC, B);  // (43, 8, 8)
    dim3 g2(64, D / K2_TC, B);                          // (64, 4, 8)

    mrl_k1<<<g1, 256, 0, stream>>>(x, h0, h1, w, (uint32_t*)y);
    mrl_k2<<<g2, 256, 0, stream>>>(h0, h1, w, y);
}

// Round 4
// 199.817 us; speedup vs baseline: 5.3600x; 2.3035x over previous
//
#include <hip/hip_runtime.h>
#include <hip/hip_bf16.h>
#include <stdint.h>

namespace {

constexpr int L = 8192;
constexpr int D = 256;

// K1: levels 0..5 (dilation 1..32). Block: 512 thr = 16 t-groups x 32 channels,
// R=16 t per thread -> 256 staged t, first 64 are halo, 192 valid outputs.
constexpr int K1_TC  = 32;
constexpr int K1_R   = 16;
constexpr int K1_OUT = 192;
constexpr int EXS1   = K1_R + 1;   // 17: odd stride -> 2-way bank alias (free)

// K2: levels 6..12 (t1-dilation 1..64). Block: 512 thr = 16 t1-groups x 32 ch,
// R=8 t1 per thread -> 16*8 = 128 = full t1 range.
constexpr int K2_TC = 32;
constexpr int K2_R  = 8;
constexpr int EXS2  = K2_R + 1;    // 9

// pack {bf16(y1) low 16, bf16(a6) high 16}
__device__ __forceinline__ uint32_t pk2(float ylo, float ahi) {
    union { __hip_bfloat16 h; uint16_t u; } a, b;
    a.h = __float2bfloat16(ylo);
    b.h = __float2bfloat16(ahi);
    return ((uint32_t)b.u << 16) | (uint32_t)a.u;
}
__device__ __forceinline__ float up_lo(uint32_t u) { return __uint_as_float(u << 16); }
__device__ __forceinline__ float up_hi(uint32_t u) { return __uint_as_float(u & 0xffff0000u); }

// ---------------- Kernel 1: levels 0..5 ----------------
__global__ __launch_bounds__(512, 2)
void mrl_k1(const float* __restrict__ x, const float* __restrict__ h0,
            const float* __restrict__ h1, const float* __restrict__ w,
            uint32_t* __restrict__ out_pk) {
    __shared__ float ex[512 * EXS1];
    const int tid = threadIdx.x;
    const int tc  = tid & (K1_TC - 1);
    const int tt  = tid / K1_TC;              // 0..15
    const int c   = blockIdx.y * K1_TC + tc;
    const int b   = blockIdx.z;
    const int t0  = blockIdx.x * K1_OUT;
    const int ts  = t0 - 64 + tt * K1_R;      // first staged t of this thread

    const float h0c0 = h0[2*c], h0c1 = h0[2*c+1];
    const float h1c0 = h1[2*c], h1c1 = h1[2*c+1];
    const float w0   = w[c];

    const float* xp = x + (size_t)b * L * D + c;
    float a[K1_R], y[K1_R];
    if (ts >= 0 && ts + K1_R <= L) {          // interior: unguarded loads
#pragma unroll
        for (int i = 0; i < K1_R; ++i) {
            const float v = xp[(size_t)(ts + i) * D];
            a[i] = v; y[i] = w0 * v;
        }
    } else {
#pragma unroll
        for (int i = 0; i < K1_R; ++i) {
            const int t = ts + i;
            const float v = (t >= 0 && t < L) ? xp[(size_t)t * D] : 0.f;
            a[i] = v; y[i] = w0 * v;
        }
    }

#pragma unroll
    for (int j = 0; j < 6; ++j) {
        const int d = 1 << j;                 // compile-time after unroll
        const float wj = w[(j + 1) * D + c];
        if (d < K1_R) {
            // publish top d old values for right neighbor
#pragma unroll
            for (int k = 0; k < d; ++k) ex[tid * EXS1 + k] = a[K1_R - d + k];
            __syncthreads();
            const int nsrc = (tt > 0) ? (tid - K1_TC) : tid;
            // descending i: in-register lookback reads not-yet-updated regs
#pragma unroll
            for (int i = K1_R - 1; i >= 0; --i) {
                float look;
                if (i >= d) look = a[i - d];
                else {
                    const float hv = ex[nsrc * EXS1 + i];
                    look = (tt > 0) ? hv : 0.f;
                }
                const float bv = look * h1c0 + a[i] * h1c1;
                y[i] = fmaf(wj, bv, y[i]);
                a[i] = look * h0c0 + a[i] * h0c1;
            }
        } else {                              // d = 16 or 32: full-slab, neighbor m = d/R
            const int m = d / K1_R;           // 1 or 2
#pragma unroll
            for (int k = 0; k < K1_R; ++k) ex[tid * EXS1 + k] = a[k];
            __syncthreads();
            const bool ok = (tt >= m);
            const int nsrc = ok ? (tid - m * K1_TC) : tid;
#pragma unroll
            for (int i = 0; i < K1_R; ++i) {
                const float hv = ex[nsrc * EXS1 + i];
                const float look = ok ? hv : 0.f;   // slot i of group tt-m = pos p-d
                const float bv = look * h1c0 + a[i] * h1c1;
                y[i] = fmaf(wj, bv, y[i]);
                a[i] = look * h0c0 + a[i] * h0c1;
            }
        }
        __syncthreads();
    }

    if (tt >= 4) {                            // valid outputs [t0, t0+192)
        uint32_t* op = out_pk + (size_t)b * L * D + c;
        if (ts + K1_R <= L) {
#pragma unroll
            for (int i = 0; i < K1_R; ++i) op[(size_t)(ts + i) * D] = pk2(y[i], a[i]);
        } else {
#pragma unroll
            for (int i = 0; i < K1_R; ++i)
                if (ts + i < L) op[(size_t)(ts + i) * D] = pk2(y[i], a[i]);
        }
    }
}

// ---------------- Kernel 2: levels 6..12 + final terms ----------------
// t = t1*64 + t2; levels 6..12 couple only along t1 (length 128).
// Reads packed {y1,a6} from d_out, overwrites in place with final f32 y.
__global__ __launch_bounds__(512, 2)
void mrl_k2(const float* __restrict__ h0, const float* __restrict__ h1,
            const float* __restrict__ w, float* __restrict__ y) {
    __shared__ float ex[512 * EXS2];
    const uint32_t* yin = (const uint32_t*)y;
    const int tid = threadIdx.x;
    const int tc  = tid & (K2_TC - 1);
    const int tt  = tid / K2_TC;              // 0..15
    const int t2  = blockIdx.x;               // 0..63
    const int c   = blockIdx.y * K2_TC + tc;
    const int b   = blockIdx.z;

    const float h0c0 = h0[2*c], h0c1 = h0[2*c+1];
    const float h1c0 = h1[2*c], h1c1 = h1[2*c+1];

    const size_t base = ((size_t)b * L + t2) * D + c;   // t1 stride = 64*D
    float a[K2_R], yv[K2_R];
#pragma unroll
    for (int i = 0; i < K2_R; ++i) {
        const uint32_t u = yin[base + (size_t)(tt * K2_R + i) * 64 * D];
        a[i]  = up_hi(u);
        yv[i] = up_lo(u);
    }

#pragma unroll
    for (int j = 0; j < 7; ++j) {
        const int d = 1 << j;                 // t1 units: 1..64
        const float wj = w[(j + 7) * D + c];
        if (d < K2_R) {
#pragma unroll
            for (int k = 0; k < d; ++k) ex[tid * EXS2 + k] = a[K2_R - d + k];
            __syncthreads();
            const int nsrc = (tt > 0) ? (tid - K2_TC) : tid;
#pragma unroll
            for (int i = K2_R - 1; i >= 0; --i) {
                float look;
                if (i >= d) look = a[i - d];
                else {
                    const float hv = ex[nsrc * EXS2 + i];
                    look = (tt > 0) ? hv : 0.f;
                }
                const float bv = look * h1c0 + a[i] * h1c1;
                yv[i] = fmaf(wj, bv, yv[i]);
                a[i] = look * h0c0 + a[i] * h0c1;
            }
        } else {                              // d = 8,16,32,64: neighbor m = d/R
            const int m = d / K2_R;           // 1,2,4,8
#pragma unroll
            for (int k = 0; k < K2_R; ++k) ex[tid * EXS2 + k] = a[k];
            __syncthreads();
            const bool ok = (tt >= m);
            const int nsrc = ok ? (tid - m * K2_TC) : tid;
#pragma unroll
            for (int i = 0; i < K2_R; ++i) {
                const float hv = ex[nsrc * EXS2 + i];
                const float look = ok ? hv : 0.f;
                const float bv = look * h1c0 + a[i] * h1c1;
                yv[i] = fmaf(wj, bv, yv[i]);
                a[i] = look * h0c0 + a[i] * h0c1;
            }
        }
        __syncthreads();
    }

    const float w14 = w[14 * D + c];
#pragma unroll
    for (int i = 0; i < K2_R; ++i) {
        yv[i] = fmaf(w14, a[i], yv[i]);
        y[base + (size_t)(tt * K2_R + i) * 64 * D] = yv[i];
    }
}

} // namespace

extern "C" void kernel_launch(void* const* d_in, const int* in_sizes, int n_in,
                              void* d_out, int out_size, void* d_ws, size_t ws_size,
                              hipStream_t stream) {
    const float* x  = (const float*)d_in[0];
    const float* h0 = (const float*)d_in[1];
    const float* h1 = (const float*)d_in[2];
    const float* w  = (const float*)d_in[3];
    float* y = (float*)d_out;
    (void)d_ws; (void)ws_size;

    const int B = in_sizes[0] / (L * D);   // = 8

    dim3 g1((L + K1_OUT - 1) / K1_OUT, D / K1_TC, B);  // (43, 8, 8)
    dim3 g2(64, D / K2_TC, B);                          // (64, 8, 8)

    mrl_k1<<<g1, 512, 0, stream>>>(x, h0, h1, w, (uint32_t*)y);
    mrl_k2<<<g2, 512, 0, stream>>>(h0, h1, w, y);
}

// Round 5
// 174.242 us; speedup vs baseline: 6.1467x; 1.1468x over previous
//
#include <hip/hip_runtime.h>
#include <hip/hip_bf16.h>
#include <stdint.h>

namespace {

constexpr int L = 8192;
constexpr int D = 256;

// K1: levels 0..5 (dilation 1..32). Block 256 thr = 4 waves, 32-channel tile,
// 256 staged t (64 halo + 192 valid). Wave-pass = 1 channel; lane owns 4 t.
constexpr int K1_CT  = 32;
constexpr int K1_OUT = 192;
constexpr int K1_S   = 265;   // LDS words per channel row (phi1 max 262)

// K2: levels 6..12 (t1-dilation 1..64). Block 256 thr, 32-channel x 2-t2 tile,
// full t1 range 128. Wave-pass = 1 (channel,t2); lane owns 2 t1.
constexpr int K2_CT = 32;
constexpr int K2_T2 = 2;
constexpr int K2_S  = 131;    // LDS words per (c,t2) row (phi2 max 130)

__device__ __forceinline__ int phi1(int p) { return p + (p >> 5); }
__device__ __forceinline__ int phi2(int t) { return t + (t >> 5); }

// pack {bf16(y1) low 16, bf16(a6) high 16}
__device__ __forceinline__ uint32_t pk2(float ylo, float ahi) {
    union { __hip_bfloat16 h; uint16_t u; } a, b;
    a.h = __float2bfloat16(ylo);
    b.h = __float2bfloat16(ahi);
    return ((uint32_t)b.u << 16) | (uint32_t)a.u;
}
__device__ __forceinline__ float up_lo(uint32_t u) { return __uint_as_float(u << 16); }
__device__ __forceinline__ float up_hi(uint32_t u) { return __uint_as_float(u & 0xffff0000u); }

// one dilation level over a 4-t register run (looks l0..l3 captured pre-update)
__device__ __forceinline__ void lvl4(float (&a)[4], float (&y)[4],
                                     float l0, float l1, float l2, float l3,
                                     float h00, float h01, float h10, float h11,
                                     float wj) {
    const float lk[4] = {l0, l1, l2, l3};
#pragma unroll
    for (int i = 0; i < 4; ++i) {
        const float bv = lk[i] * h10 + a[i] * h11;
        y[i] = fmaf(wj, bv, y[i]);
        a[i] = lk[i] * h00 + a[i] * h01;
    }
}

__device__ __forceinline__ void lvl2f(float& a0, float& a1, float& y0, float& y1,
                                      float l0, float l1,
                                      float h00, float h01, float h10, float h11,
                                      float wj) {
    const float bv0 = l0 * h10 + a0 * h11;
    const float bv1 = l1 * h10 + a1 * h11;
    y0 = fmaf(wj, bv0, y0);
    y1 = fmaf(wj, bv1, y1);
    a0 = l0 * h00 + a0 * h01;
    a1 = l1 * h00 + a1 * h01;
}

// ---------------- Kernel 1: levels 0..5 ----------------
__global__ __launch_bounds__(256, 4)
void mrl_k1(const float* __restrict__ x, const float* __restrict__ h0,
            const float* __restrict__ h1, const float* __restrict__ w,
            uint32_t* __restrict__ out_pk) {
    __shared__ uint32_t lds[K1_CT * K1_S];   // 33.9 KB; f32 x, then packed out
    const int tid = threadIdx.x;
    const int b  = blockIdx.z;
    const int c0 = blockIdx.y * K1_CT;
    const int t0 = blockIdx.x * K1_OUT;
    const int tsb = t0 - 64;                 // first staged t (64-t halo)

    // ---- stage x coalesced (float4 over channels) -> channel-major swizzled LDS
    {
        const int cq = (tid & 7) * 4;
        const int tr = tid >> 3;             // 0..31
        const float* xb = x + (size_t)b * L * D + c0 + cq;
#pragma unroll
        for (int it = 0; it < 8; ++it) {
            const int p = it * 32 + tr;
            const int t = tsb + p;
            float4 v = make_float4(0.f, 0.f, 0.f, 0.f);
            if (t >= 0 && t < L) v = *reinterpret_cast<const float4*>(xb + (size_t)t * D);
            const int ph = phi1(p);
            lds[(cq + 0) * K1_S + ph] = __float_as_uint(v.x);
            lds[(cq + 1) * K1_S + ph] = __float_as_uint(v.y);
            lds[(cq + 2) * K1_S + ph] = __float_as_uint(v.z);
            lds[(cq + 3) * K1_S + ph] = __float_as_uint(v.w);
        }
    }
    __syncthreads();

    // ---- wave-local passes: 8 channels per wave, lane owns t-run [4l, 4l+4)
    {
        const int lane = tid & 63;
        const int wv   = tid >> 6;           // 0..3
        const int p0   = 4 * lane;
#pragma unroll
        for (int q = 0; q < 8; ++q) {
            const int cl = wv + 4 * q;       // wave-private channel rows
            const int c  = c0 + cl;
            const float h00 = h0[2*c], h01 = h0[2*c+1];
            const float h10 = h1[2*c], h11 = h1[2*c+1];
            const int base = cl * K1_S;
            float a[4], y[4];
            {
                const float w0 = w[c];
#pragma unroll
                for (int i = 0; i < 4; ++i) {
                    a[i] = __uint_as_float(lds[base + phi1(p0 + i)]);
                    y[i] = w0 * a[i];
                }
            }
            // d=1: look = {lane-1 a3, a0, a1, a2}
            lvl4(a, y, __shfl_up(a[3], 1), a[0], a[1], a[2],
                 h00, h01, h10, h11, w[1*D + c]);
            // d=2
            lvl4(a, y, __shfl_up(a[2], 1), __shfl_up(a[3], 1), a[0], a[1],
                 h00, h01, h10, h11, w[2*D + c]);
            // d=4 (m=1), 8 (m=2), 16 (m=4), 32 (m=8): full slab of lane-m
            lvl4(a, y, __shfl_up(a[0], 1), __shfl_up(a[1], 1),
                       __shfl_up(a[2], 1), __shfl_up(a[3], 1),
                 h00, h01, h10, h11, w[3*D + c]);
            lvl4(a, y, __shfl_up(a[0], 2), __shfl_up(a[1], 2),
                       __shfl_up(a[2], 2), __shfl_up(a[3], 2),
                 h00, h01, h10, h11, w[4*D + c]);
            lvl4(a, y, __shfl_up(a[0], 4), __shfl_up(a[1], 4),
                       __shfl_up(a[2], 4), __shfl_up(a[3], 4),
                 h00, h01, h10, h11, w[5*D + c]);
            lvl4(a, y, __shfl_up(a[0], 8), __shfl_up(a[1], 8),
                       __shfl_up(a[2], 8), __shfl_up(a[3], 8),
                 h00, h01, h10, h11, w[6*D + c]);
            // shfl-clamp garbage only enters halo positions p<64 (valid p>=64
            // has receptive field >= p-63 >= 1); block 0 staged t<0 are zeros.
#pragma unroll
            for (int i = 0; i < 4; ++i)
                lds[base + phi1(p0 + i)] = pk2(y[i], a[i]);
        }
    }
    __syncthreads();

    // ---- coalesced packed store, valid p in [64, 256)
    {
        const int cq = (tid & 7) * 4;
        const int tr = tid >> 3;
        uint32_t* ob = out_pk + (size_t)b * L * D + c0 + cq;
#pragma unroll
        for (int it = 0; it < 6; ++it) {
            const int p = 64 + it * 32 + tr;
            const int t = tsb + p;
            if (t < L) {
                const int ph = phi1(p);
                uint4 v;
                v.x = lds[(cq + 0) * K1_S + ph];
                v.y = lds[(cq + 1) * K1_S + ph];
                v.z = lds[(cq + 2) * K1_S + ph];
                v.w = lds[(cq + 3) * K1_S + ph];
                *reinterpret_cast<uint4*>(ob + (size_t)t * D) = v;
            }
        }
    }
}

// ---------------- Kernel 2: levels 6..12 + final terms ----------------
// t = t1*64 + t2; coupling only along t1 (128 long). In-place on d_out.
__global__ __launch_bounds__(256, 4)
void mrl_k2(const float* __restrict__ h0, const float* __restrict__ h1,
            const float* __restrict__ w, float* __restrict__ y) {
    __shared__ uint32_t lds[K2_CT * K2_T2 * K2_S];   // 33.5 KB
    const int tid = threadIdx.x;
    const int b   = blockIdx.z;
    const int c0  = blockIdx.y * K2_CT;
    const int t2a = blockIdx.x * K2_T2;
    uint32_t* yb = reinterpret_cast<uint32_t*>(y) + (size_t)b * L * D + c0;

    // ---- stage packed {y1,a6} coalesced (uint4 over channels)
    {
        const int cq  = (tid & 7) * 4;
        const int t2i = (tid >> 3) & 1;
        const int t1r = tid >> 4;            // 0..15
#pragma unroll
        for (int it = 0; it < 8; ++it) {
            const int t1 = it * 16 + t1r;
            const int t  = t1 * 64 + t2a + t2i;
            const uint4 v = *reinterpret_cast<const uint4*>(yb + (size_t)t * D + cq);
            const int ph = phi2(t1);
            lds[((cq + 0) * 2 + t2i) * K2_S + ph] = v.x;
            lds[((cq + 1) * 2 + t2i) * K2_S + ph] = v.y;
            lds[((cq + 2) * 2 + t2i) * K2_S + ph] = v.z;
            lds[((cq + 3) * 2 + t2i) * K2_S + ph] = v.w;
        }
    }
    __syncthreads();

    // ---- wave-local passes: 16 (c,t2) rows per wave, lane owns t1 {2l, 2l+1}
    {
        const int lane = tid & 63;
        const int wv   = tid >> 6;
#pragma unroll
        for (int q = 0; q < 16; ++q) {
            const int pr = wv + 4 * q;       // wave-private row 0..63
            const int c  = c0 + (pr >> 1);
            const float h00 = h0[2*c], h01 = h0[2*c+1];
            const float h10 = h1[2*c], h11 = h1[2*c+1];
            const int base = pr * K2_S;
            float a0, a1, y0, y1v;
            {
                const uint32_t u0 = lds[base + phi2(2 * lane)];
                const uint32_t u1 = lds[base + phi2(2 * lane + 1)];
                a0 = up_hi(u0); y0  = up_lo(u0);
                a1 = up_hi(u1); y1v = up_lo(u1);
            }
            // t1-dilation 1 (global level 6): look = {lane-1 a1 (mask t1<0), a0}
            {
                const float s = __shfl_up(a1, 1);
                const float l0 = (lane >= 1) ? s : 0.f;
                lvl2f(a0, a1, y0, y1v, l0, a0, h00, h01, h10, h11, w[7*D + c]);
            }
            // t1-dilation 2,4,8,16,32,64 -> lane-m full slab, m=1..32
#pragma unroll
            for (int k = 0; k < 6; ++k) {
                const int m = 1 << k;
                const float wj = w[(8 + k) * D + c];
                const float s0 = __shfl_up(a0, m);
                const float s1 = __shfl_up(a1, m);
                const bool ok = (lane >= m);
                const float l0 = ok ? s0 : 0.f;
                const float l1 = ok ? s1 : 0.f;
                lvl2f(a0, a1, y0, y1v, l0, l1, h00, h01, h10, h11, wj);
            }
            const float w14 = w[14*D + c];
            y0  = fmaf(w14, a0, y0);
            y1v = fmaf(w14, a1, y1v);
            lds[base + phi2(2 * lane)]     = __float_as_uint(y0);
            lds[base + phi2(2 * lane + 1)] = __float_as_uint(y1v);
        }
    }
    __syncthreads();

    // ---- coalesced final f32 store
    {
        const int cq = (tid & 7) * 4;
        const int rq = tid >> 3;             // 0..31
#pragma unroll
        for (int it = 0; it < 8; ++it) {
            const int row = it * 32 + rq;    // 0..255
            const int t1 = row >> 1, t2i = row & 1;
            const int t  = t1 * 64 + t2a + t2i;
            const int ph = phi2(t1);
            uint4 v;
            v.x = lds[((cq + 0) * 2 + t2i) * K2_S + ph];
            v.y = lds[((cq + 1) * 2 + t2i) * K2_S + ph];
            v.z = lds[((cq + 2) * 2 + t2i) * K2_S + ph];
            v.w = lds[((cq + 3) * 2 + t2i) * K2_S + ph];
            *reinterpret_cast<uint4*>(yb + (size_t)t * D + cq) = v;
        }
    }
}

} // namespace

extern "C" void kernel_launch(void* const* d_in, const int* in_sizes, int n_in,
                              void* d_out, int out_size, void* d_ws, size_t ws_size,
                              hipStream_t stream) {
    const float* x  = (const float*)d_in[0];
    const float* h0 = (const float*)d_in[1];
    const float* h1 = (const float*)d_in[2];
    const float* w  = (const float*)d_in[3];
    float* y = (float*)d_out;
    (void)d_ws; (void)ws_size;

    const int B = in_sizes[0] / (L * D);   // = 8

    dim3 g1((L + K1_OUT - 1) / K1_OUT, D / K1_CT, B);  // (43, 8, 8)
    dim3 g2(64 / K2_T2, D / K2_CT, B);                 // (32, 8, 8)

    mrl_k1<<<g1, 256, 0, stream>>>(x, h0, h1, w, (uint32_t*)y);
    mrl_k2<<<g2, 256, 0, stream>>>(h0, h1, w, y);
}

// Round 6
// 164.692 us; speedup vs baseline: 6.5032x; 1.0580x over previous
//
#include <hip/hip_runtime.h>
#include <hip/hip_bf16.h>
#include <stdint.h>

namespace {

constexpr int L = 8192;
constexpr int D = 256;

// K1: levels 0..5 (dilation 1..32). Block 512 thr = 8 waves, 32-channel tile,
// 256 staged t (64 halo + 192 valid). Wave-pass = 1 channel; lane owns 4 t.
constexpr int K1_CT  = 32;
constexpr int K1_OUT = 192;
constexpr int K1_S   = 265;   // LDS words per channel row (phi1 max 262)

// K2: levels 6..12 (t1-dilation 1..64). Block 512 thr, 32-channel x 2-t2 tile,
// full t1 range 128. Wave-pass = 1 (channel,t2) row; lane owns 2 t1.
constexpr int K2_CT = 32;
constexpr int K2_T2 = 2;
constexpr int K2_S  = 131;    // LDS words per (c,t2) row (phi2 max 130)

__device__ __forceinline__ int phi1(int p) { return p + (p >> 5); }
__device__ __forceinline__ int phi2(int t) { return t + (t >> 5); }

// pack {bf16(y1) low 16, bf16(a6) high 16}
__device__ __forceinline__ uint32_t pk2(float ylo, float ahi) {
    union { __hip_bfloat16 h; uint16_t u; } a, b;
    a.h = __float2bfloat16(ylo);
    b.h = __float2bfloat16(ahi);
    return ((uint32_t)b.u << 16) | (uint32_t)a.u;
}
__device__ __forceinline__ float up_lo(uint32_t u) { return __uint_as_float(u << 16); }
__device__ __forceinline__ float up_hi(uint32_t u) { return __uint_as_float(u & 0xffff0000u); }

__device__ __forceinline__ void lvl4(float (&a)[4], float (&y)[4],
                                     float l0, float l1, float l2, float l3,
                                     float h00, float h01, float h10, float h11,
                                     float wj) {
    const float lk[4] = {l0, l1, l2, l3};
#pragma unroll
    for (int i = 0; i < 4; ++i) {
        const float bv = lk[i] * h10 + a[i] * h11;
        y[i] = fmaf(wj, bv, y[i]);
        a[i] = lk[i] * h00 + a[i] * h01;
    }
}

__device__ __forceinline__ void lvl2f(float& a0, float& a1, float& y0, float& y1,
                                      float l0, float l1,
                                      float h00, float h01, float h10, float h11,
                                      float wj) {
    const float bv0 = l0 * h10 + a0 * h11;
    const float bv1 = l1 * h10 + a1 * h11;
    y0 = fmaf(wj, bv0, y0);
    y1 = fmaf(wj, bv1, y1);
    a0 = l0 * h00 + a0 * h01;
    a1 = l1 * h00 + a1 * h01;
}

// ---------------- Kernel 1: levels 0..5 ----------------
__global__ __launch_bounds__(512, 8)
void mrl_k1(const float* __restrict__ x, const float* __restrict__ h0,
            const float* __restrict__ h1, const float* __restrict__ w,
            uint32_t* __restrict__ out_pk) {
    __shared__ uint32_t lds[K1_CT * K1_S];   // 33.9 KB; f32 x, then packed out
    __shared__ float cf[11 * K1_CT];         // rows 0..6: w0..w6; 7..10: h00,h01,h10,h11
    const int tid = threadIdx.x;
    const int b  = blockIdx.z;
    const int c0 = blockIdx.y * K1_CT;
    const int t0 = blockIdx.x * K1_OUT;
    const int tsb = t0 - 64;                 // first staged t (64-t halo)

    // ---- stage coefficients into LDS (done alongside x staging, same barrier)
    if (tid < 11 * K1_CT) {
        const int r = tid >> 5, i = tid & 31;
        float v;
        if (r < 7)       v = w[r * D + c0 + i];
        else if (r == 7) v = h0[2 * (c0 + i)];
        else if (r == 8) v = h0[2 * (c0 + i) + 1];
        else if (r == 9) v = h1[2 * (c0 + i)];
        else             v = h1[2 * (c0 + i) + 1];
        cf[tid] = v;
    }

    // ---- stage x coalesced (float4 over channels) -> channel-major swizzled LDS
    {
        const int cq = (tid & 7) * 4;
        const int tr = tid >> 3;             // 0..63
        const float* xb = x + (size_t)b * L * D + c0 + cq;
#pragma unroll
        for (int it = 0; it < 4; ++it) {
            const int p = it * 64 + tr;
            const int t = tsb + p;
            float4 v = make_float4(0.f, 0.f, 0.f, 0.f);
            if (t >= 0 && t < L) v = *reinterpret_cast<const float4*>(xb + (size_t)t * D);
            const int ph = phi1(p);
            lds[(cq + 0) * K1_S + ph] = __float_as_uint(v.x);
            lds[(cq + 1) * K1_S + ph] = __float_as_uint(v.y);
            lds[(cq + 2) * K1_S + ph] = __float_as_uint(v.z);
            lds[(cq + 3) * K1_S + ph] = __float_as_uint(v.w);
        }
    }
    __syncthreads();

    // ---- wave-local passes: 4 channels per wave, lane owns t-run [4l, 4l+4)
    {
        const int lane = tid & 63;
        const int wv   = tid >> 6;           // 0..7
        const int p0   = 4 * lane;
#pragma unroll
        for (int q = 0; q < 4; ++q) {
            const int cl = wv + 8 * q;       // wave-private channel row
            const float h00 = cf[7*K1_CT + cl], h01 = cf[8*K1_CT + cl];
            const float h10 = cf[9*K1_CT + cl], h11 = cf[10*K1_CT + cl];
            const int base = cl * K1_S;
            float a[4], y[4];
            {
                const float w0 = cf[cl];
#pragma unroll
                for (int i = 0; i < 4; ++i) {
                    a[i] = __uint_as_float(lds[base + phi1(p0 + i)]);
                    y[i] = w0 * a[i];
                }
            }
            // d=1
            lvl4(a, y, __shfl_up(a[3], 1), a[0], a[1], a[2],
                 h00, h01, h10, h11, cf[1*K1_CT + cl]);
            // d=2
            lvl4(a, y, __shfl_up(a[2], 1), __shfl_up(a[3], 1), a[0], a[1],
                 h00, h01, h10, h11, cf[2*K1_CT + cl]);
            // d=4,8,16,32: full slab of lane-m, m=1,2,4,8
            lvl4(a, y, __shfl_up(a[0], 1), __shfl_up(a[1], 1),
                       __shfl_up(a[2], 1), __shfl_up(a[3], 1),
                 h00, h01, h10, h11, cf[3*K1_CT + cl]);
            lvl4(a, y, __shfl_up(a[0], 2), __shfl_up(a[1], 2),
                       __shfl_up(a[2], 2), __shfl_up(a[3], 2),
                 h00, h01, h10, h11, cf[4*K1_CT + cl]);
            lvl4(a, y, __shfl_up(a[0], 4), __shfl_up(a[1], 4),
                       __shfl_up(a[2], 4), __shfl_up(a[3], 4),
                 h00, h01, h10, h11, cf[5*K1_CT + cl]);
            lvl4(a, y, __shfl_up(a[0], 8), __shfl_up(a[1], 8),
                       __shfl_up(a[2], 8), __shfl_up(a[3], 8),
                 h00, h01, h10, h11, cf[6*K1_CT + cl]);
            // shfl-clamp garbage contaminates only p<63 (halo); valid p>=64
            // depends on initial x only down to p-63 >= 1. Block 0's t<0 zeros.
#pragma unroll
            for (int i = 0; i < 4; ++i)
                lds[base + phi1(p0 + i)] = pk2(y[i], a[i]);
        }
    }
    __syncthreads();

    // ---- coalesced packed store, valid p in [64, 256)
    {
        const int cq = (tid & 7) * 4;
        const int tr = tid >> 3;             // 0..63
        uint32_t* ob = out_pk + (size_t)b * L * D + c0 + cq;
#pragma unroll
        for (int it = 0; it < 3; ++it) {
            const int p = 64 + it * 64 + tr;
            const int t = tsb + p;
            if (t < L) {
                const int ph = phi1(p);
                uint4 v;
                v.x = lds[(cq + 0) * K1_S + ph];
                v.y = lds[(cq + 1) * K1_S + ph];
                v.z = lds[(cq + 2) * K1_S + ph];
                v.w = lds[(cq + 3) * K1_S + ph];
                *reinterpret_cast<uint4*>(ob + (size_t)t * D) = v;
            }
        }
    }
}

// ---------------- Kernel 2: levels 6..12 + final terms ----------------
// t = t1*64 + t2; coupling only along t1 (128 long). In-place on d_out.
__global__ __launch_bounds__(512, 8)
void mrl_k2(const float* __restrict__ h0, const float* __restrict__ h1,
            const float* __restrict__ w, float* __restrict__ y) {
    __shared__ uint32_t lds[K2_CT * K2_T2 * K2_S];   // 33.5 KB
    __shared__ float cf[12 * K2_CT];         // rows 0..7: w7..w14; 8..11: h00,h01,h10,h11
    const int tid = threadIdx.x;
    const int b   = blockIdx.z;
    const int c0  = blockIdx.y * K2_CT;
    const int t2a = blockIdx.x * K2_T2;
    uint32_t* yb = reinterpret_cast<uint32_t*>(y) + (size_t)b * L * D + c0;

    if (tid < 12 * K2_CT) {
        const int r = tid >> 5, i = tid & 31;
        float v;
        if (r < 8)        v = w[(r + 7) * D + c0 + i];
        else if (r == 8)  v = h0[2 * (c0 + i)];
        else if (r == 9)  v = h0[2 * (c0 + i) + 1];
        else if (r == 10) v = h1[2 * (c0 + i)];
        else              v = h1[2 * (c0 + i) + 1];
        cf[tid] = v;
    }

    // ---- stage packed {y1,a6} coalesced (uint4 over channels)
    {
        const int cq  = (tid & 7) * 4;
        const int t2i = (tid >> 3) & 1;
        const int t1r = tid >> 4;            // 0..31
#pragma unroll
        for (int it = 0; it < 4; ++it) {
            const int t1 = it * 32 + t1r;
            const int t  = t1 * 64 + t2a + t2i;
            const uint4 v = *reinterpret_cast<const uint4*>(yb + (size_t)t * D + cq);
            const int ph = phi2(t1);
            lds[((cq + 0) * 2 + t2i) * K2_S + ph] = v.x;
            lds[((cq + 1) * 2 + t2i) * K2_S + ph] = v.y;
            lds[((cq + 2) * 2 + t2i) * K2_S + ph] = v.z;
            lds[((cq + 3) * 2 + t2i) * K2_S + ph] = v.w;
        }
    }
    __syncthreads();

    // ---- wave-local passes: 8 (c,t2) rows per wave, lane owns t1 {2l, 2l+1}
    {
        const int lane = tid & 63;
        const int wv   = tid >> 6;           // 0..7
#pragma unroll
        for (int q = 0; q < 8; ++q) {
            const int pr = wv + 8 * q;       // wave-private row 0..63
            const int cl = pr >> 1;
            const float h00 = cf[8*K2_CT + cl],  h01 = cf[9*K2_CT + cl];
            const float h10 = cf[10*K2_CT + cl], h11 = cf[11*K2_CT + cl];
            const int base = pr * K2_S;
            float a0, a1, y0, y1v;
            {
                const uint32_t u0 = lds[base + phi2(2 * lane)];
                const uint32_t u1 = lds[base + phi2(2 * lane + 1)];
                a0 = up_hi(u0); y0  = up_lo(u0);
                a1 = up_hi(u1); y1v = up_lo(u1);
            }
            // t1-dilation 1 (level 6)
            {
                const float s = __shfl_up(a1, 1);
                const float l0 = (lane >= 1) ? s : 0.f;
                lvl2f(a0, a1, y0, y1v, l0, a0, h00, h01, h10, h11, cf[cl]);
            }
            // t1-dilation 2,4,8,16,32,64 -> lane-m full slab, m=1..32
#pragma unroll
            for (int k = 0; k < 6; ++k) {
                const int m = 1 << k;
                const float wj = cf[(1 + k) * K2_CT + cl];
                const float s0 = __shfl_up(a0, m);
                const float s1 = __shfl_up(a1, m);
                const bool ok = (lane >= m);
                const float l0 = ok ? s0 : 0.f;
                const float l1 = ok ? s1 : 0.f;
                lvl2f(a0, a1, y0, y1v, l0, l1, h00, h01, h10, h11, wj);
            }
            const float w14 = cf[7 * K2_CT + cl];
            y0  = fmaf(w14, a0, y0);
            y1v = fmaf(w14, a1, y1v);
            lds[base + phi2(2 * lane)]     = __float_as_uint(y0);
            lds[base + phi2(2 * lane + 1)] = __float_as_uint(y1v);
        }
    }
    __syncthreads();

    // ---- coalesced final f32 store
    {
        const int cq = (tid & 7) * 4;
        const int rq = tid >> 3;             // 0..63
#pragma unroll
        for (int it = 0; it < 4; ++it) {
            const int row = it * 64 + rq;    // 0..255
            const int t1 = row >> 1, t2i = row & 1;
            const int t  = t1 * 64 + t2a + t2i;
            const int ph = phi2(t1);
            uint4 v;
            v.x = lds[((cq + 0) * 2 + t2i) * K2_S + ph];
            v.y = lds[((cq + 1) * 2 + t2i) * K2_S + ph];
            v.z = lds[((cq + 2) * 2 + t2i) * K2_S + ph];
            v.w = lds[((cq + 3) * 2 + t2i) * K2_S + ph];
            *reinterpret_cast<uint4*>(yb + (size_t)t * D + cq) = v;
        }
    }
}

} // namespace

extern "C" void kernel_launch(void* const* d_in, const int* in_sizes, int n_in,
                              void* d_out, int out_size, void* d_ws, size_t ws_size,
                              hipStream_t stream) {
    const float* x  = (const float*)d_in[0];
    const float* h0 = (const float*)d_in[1];
    const float* h1 = (const float*)d_in[2];
    const float* w  = (const float*)d_in[3];
    float* y = (float*)d_out;
    (void)d_ws; (void)ws_size;

    const int B = in_sizes[0] / (L * D);   // = 8

    dim3 g1((L + K1_OUT - 1) / K1_OUT, D / K1_CT, B);  // (43, 8, 8)
    dim3 g2(64 / K2_T2, D / K2_CT, B);                 // (32, 8, 8)

    mrl_k1<<<g1, 512, 0, stream>>>(x, h0, h1, w, (uint32_t*)y);
    mrl_k2<<<g2, 512, 0, stream>>>(h0, h1, w, y);
}